// Round 5
// baseline (56.907 us; speedup 1.0000x reference)
//
#include <hip/hip_runtime.h>
#include <math.h>

#define BROWS 2097152
#define NTH 256
#define NBLOCKS (BROWS / NTH)   // 8192 blocks, one 256-row chunk each
#define FINAL_NTH 1024

constexpr float FEPS = 1e-6f;

__device__ __forceinline__ float wave_reduce_f(float v) {
#pragma unroll
    for (int off = 32; off > 0; off >>= 1) v += __shfl_down(v, off, 64);
    return v;
}

__device__ __forceinline__ double wave_reduce_d(double v) {
#pragma unroll
    for (int off = 32; off > 0; off >>= 1) v += __shfl_down(v, off, 64);
    return v;
}

// acc slots: 0..4 = loss sums heads 0..4, 5 = softmax mask count, 6 = success count
__global__ __launch_bounds__(256) void loss_main(
    const float* __restrict__ out0, const float* __restrict__ out1,
    const float* __restrict__ out2, const float* __restrict__ out3,
    const float* __restrict__ out4, const float* __restrict__ pos_dist,
    const int* __restrict__ targets, float* __restrict__ partials)
{
    // Per-WAVE staging slices: producer == consumer wave, so no __syncthreads
    // is needed between ds_write and ds_read (lgkmcnt ordering only).
    __shared__ int tl[4][15 * 64];   // 4 waves x 960 ints = 15360 B
    __shared__ float sred[4][7];

    // uniform -> scalarized s_loads
    float pd[15];
#pragma unroll
    for (int j = 0; j < 15; ++j) pd[j] = pos_dist[j];

    const int tid = threadIdx.x;
    const int lane = tid & 63;
    const int wave = tid >> 6;
    const int row = blockIdx.x * NTH + tid;
    const int wrow0 = blockIdx.x * NTH + wave * 64;   // wave's first row

    // ---- wave-private coalesced staging of this wave's 64 rows of targets ----
    const long tb = (long)wrow0 * 15;
#pragma unroll
    for (int k = 0; k < 15; ++k)
        tl[wave][k * 64 + lane] = targets[tb + k * 64 + lane];

    // ---- naturally-coalesced direct loads (overlap with staging latency) ----
    const float x0 = out0[row];
    const float x3 = out3[row];
    const float x4 = out4[row];
    const float4 q2 = ((const float4*)out2)[row];
    const float4 pa = ((const float4*)out1)[(long)row * 2 + 0];
    const float4 pb = ((const float4*)out1)[(long)row * 2 + 1];

    // own-wave LDS readback (compiler inserts lgkmcnt wait; no barrier)
    int t[15];
#pragma unroll
    for (int j = 0; j < 15; ++j) t[j] = tl[wave][lane * 15 + j];

    float acc0, acc1 = 0.f, acc2 = 0.f, acc3, acc4;
    float cnt5 = 0.f, succ = 0.f;

    // ---- binary heads 0,3,4: pick log-arg before the log ----
    {
        float p = __builtin_amdgcn_rcpf(1.f + __expf(-x0));
        p = fminf(fmaxf(p, FEPS), 1.f - FEPS);
        float om = 1.f - p;
        bool pos = t[0] != 0;
        float larg = pos ? p : om;
        float quad = pos ? om : p;
        float coef = pos ? (1.f - pd[0]) : pd[0];
        acc0 = __logf(larg) * quad * quad * coef;
        succ += ((x0 > 0.f) == pos) ? 1.f : 0.f;
    }
    {
        float p = __builtin_amdgcn_rcpf(1.f + __expf(-x3));
        p = fminf(fmaxf(p, FEPS), 1.f - FEPS);
        float om = 1.f - p;
        bool pos = t[13] != 0;
        float larg = pos ? p : om;
        float quad = pos ? om : p;
        float coef = pos ? (1.f - pd[13]) : pd[13];
        acc3 = __logf(larg) * quad * quad * coef;
        succ += ((x3 > 0.f) == pos) ? 1.f : 0.f;
    }
    {
        float p = __builtin_amdgcn_rcpf(1.f + __expf(-x4));
        p = fminf(fmaxf(p, FEPS), 1.f - FEPS);
        float om = 1.f - p;
        bool pos = t[14] != 0;
        float larg = pos ? p : om;
        float quad = pos ? om : p;
        float coef = pos ? (1.f - pd[14]) : pd[14];
        acc4 = __logf(larg) * quad * quad * coef;
        succ += ((x4 > 0.f) == pos) ? 1.f : 0.f;
    }

    // ---- head 1: softmax probabilities (8) ----
    {
        const float o[8] = {pa.x, pa.y, pa.z, pa.w, pb.x, pb.y, pb.z, pb.w};
        int am_gt = 0;
#pragma unroll
        for (int j = 7; j >= 0; --j)
            if (t[1 + j] != 0) am_gt = j;               // first 1 (or 0 if none)
        float best = o[0];
        int am_o = 0;
#pragma unroll
        for (int j = 1; j < 8; ++j)
            if (o[j] > best) { best = o[j]; am_o = j; } // first max
#pragma unroll
        for (int j = 0; j < 8; ++j) {
            float m = (t[1 + j] != 0) ? 1.f : 0.f;
            float om = 1.f - o[j];
            acc1 += m * (__logf(o[j]) * om * om * (1.f - pd[1 + j]));
            cnt5 += m;
        }
        succ += (am_gt == am_o) ? 1.f : 0.f;
    }

    // ---- head 2: weighted BCE on logits (4) ----
    {
        const float o2v[4] = {q2.x, q2.y, q2.z, q2.w};
#pragma unroll
        for (int j = 0; j < 4; ++j) {
            float o = o2v[j];
            bool g = t[9 + j] != 0;
            float w = pd[9 + j];
            float weight = g ? (1.f - w) : w;
            float bce = fmaxf(o, 0.f) - (g ? o : 0.f)
                      + __logf(1.f + __expf(-fabsf(o)));
            acc2 += weight * bce;
            succ += ((o > 0.5f) == g) ? 1.f : 0.f;
        }
    }

    // ---- block reduction (single barrier at end of kernel) ----
    {
        float accv[7] = {acc0, acc1, acc2, acc3, acc4, cnt5, succ};
#pragma unroll
        for (int k = 0; k < 7; ++k) {
            float v = wave_reduce_f(accv[k]);
            if (lane == 0) sred[wave][k] = v;
        }
    }
    __syncthreads();
    if (tid == 0) {
#pragma unroll
        for (int k = 0; k < 7; ++k) {
            float s = sred[0][k] + sred[1][k] + sred[2][k] + sred[3][k];
            partials[(long)blockIdx.x * 8 + k] = s;
        }
    }
}

__global__ __launch_bounds__(FINAL_NTH) void loss_final(
    const float* __restrict__ partials, int nblocks, float* __restrict__ out)
{
    double acc[7] = {0, 0, 0, 0, 0, 0, 0};
    for (int b = threadIdx.x; b < nblocks; b += FINAL_NTH) {
        const float4* pp = (const float4*)(partials + (long)b * 8);
        float4 a = pp[0], bb = pp[1];
        acc[0] += a.x; acc[1] += a.y; acc[2] += a.z; acc[3] += a.w;
        acc[4] += bb.x; acc[5] += bb.y; acc[6] += bb.z;
    }

    __shared__ double sd[16][7];
    const int lane = threadIdx.x & 63;
    const int wave = threadIdx.x >> 6;
#pragma unroll
    for (int k = 0; k < 7; ++k) {
        double v = wave_reduce_d(acc[k]);
        if (lane == 0) sd[wave][k] = v;
    }
    __syncthreads();
    if (threadIdx.x == 0) {
        double s[7];
#pragma unroll
        for (int k = 0; k < 7; ++k) {
            double t = 0.0;
#pragma unroll
            for (int w = 0; w < 16; ++w) t += sd[w][k];
            s[k] = t;
        }

        const double Bd = (double)BROWS;
        double l0 = -(s[0] / Bd);
        double num = s[5];
        double l1 = (num > 0.0) ? -(s[1] / fmax(num, 1.0)) : 0.0;
        double l2 = s[2] / (Bd * 4.0);
        double l3 = -(s[3] / Bd);
        double l4 = -(s[4] / Bd);
        out[0] = (float)(l0 + l1 + l2 + l3 + l4);
        out[1] = (float)(s[6] / 8.0);
    }
}

extern "C" void kernel_launch(void* const* d_in, const int* in_sizes, int n_in,
                              void* d_out, int out_size, void* d_ws, size_t ws_size,
                              hipStream_t stream) {
    const float* out0 = (const float*)d_in[0];
    const float* out1 = (const float*)d_in[1];
    const float* out2 = (const float*)d_in[2];
    const float* out3 = (const float*)d_in[3];
    const float* out4 = (const float*)d_in[4];
    const float* pos_dist = (const float*)d_in[5];
    const int* targets = (const int*)d_in[6];
    float* out = (float*)d_out;
    float* partials = (float*)d_ws;

    loss_main<<<NBLOCKS, NTH, 0, stream>>>(
        out0, out1, out2, out3, out4, pos_dist, targets, partials);
    loss_final<<<1, FINAL_NTH, 0, stream>>>(partials, NBLOCKS, out);
}

// Round 6
// 52.075 us; speedup vs baseline: 1.0928x; 1.0928x over previous
//
#include <hip/hip_runtime.h>
#include <math.h>

#define BROWS 2097152
#define NTH 256
#define CHUNKS_PER_BLOCK 4
#define NBLOCKS (BROWS / (NTH * CHUNKS_PER_BLOCK))   // 2048
#define FINAL_NTH 256

constexpr float FEPS = 1e-6f;

__device__ __forceinline__ float wave_reduce_f(float v) {
#pragma unroll
    for (int off = 32; off > 0; off >>= 1) v += __shfl_down(v, off, 64);
    return v;
}

__device__ __forceinline__ double wave_reduce_d(double v) {
#pragma unroll
    for (int off = 32; off > 0; off >>= 1) v += __shfl_down(v, off, 64);
    return v;
}

// acc slots: 0..4 = loss sums heads 0..4, 5 = softmax mask count, 6 = success count
__global__ __launch_bounds__(256) void loss_main(
    const float* __restrict__ out0, const float* __restrict__ out1,
    const float* __restrict__ out2, const float* __restrict__ out3,
    const float* __restrict__ out4, const float* __restrict__ pos_dist,
    const int* __restrict__ targets, float* __restrict__ partials)
{
    // Per-WAVE staging slices: producer == consumer wave -> no __syncthreads
    // in the chunk loop (lgkmcnt ordering only).
    __shared__ int tl[4][15 * 64];   // 15360 B
    __shared__ float sred[4][5];

    float pd[15];
#pragma unroll
    for (int j = 0; j < 15; ++j) pd[j] = pos_dist[j];

    const int tid = threadIdx.x;
    const int lane = tid & 63;
    const int wave = tid >> 6;

    float acc0 = 0.f, acc1 = 0.f, acc2 = 0.f, acc3 = 0.f, acc4 = 0.f;
    long long succ_i = 0, cnt5_i = 0;     // wave-uniform (ballot/popcount path)

#pragma unroll
    for (int c = 0; c < CHUNKS_PER_BLOCK; ++c) {
        const int chunk = blockIdx.x * CHUNKS_PER_BLOCK + c;
        const int row = chunk * NTH + tid;
        const int wrow0 = chunk * NTH + wave * 64;

        // ---- wave-private coalesced staging of 64 rows of targets ----
        const long tb = (long)wrow0 * 15;
#pragma unroll
        for (int k = 0; k < 15; ++k)
            tl[wave][k * 64 + lane] = targets[tb + k * 64 + lane];

        // ---- naturally-coalesced float loads (overlap with staging) ----
        const float x0 = out0[row];
        const float x3 = out3[row];
        const float x4 = out4[row];
        const float4 q2 = ((const float4*)out2)[row];
        const float4 pa = ((const float4*)out1)[(long)row * 2 + 0];
        const float4 pb = ((const float4*)out1)[(long)row * 2 + 1];

        int t[15];
#pragma unroll
        for (int j = 0; j < 15; ++j) t[j] = tl[wave][lane * 15 + j];

        // ---- binary heads 0,3,4 ----
        {
            float p = __builtin_amdgcn_rcpf(1.f + __expf(-x0));
            p = fminf(fmaxf(p, FEPS), 1.f - FEPS);
            float om = 1.f - p;
            bool pos = t[0] != 0;
            float larg = pos ? p : om;
            float quad = pos ? om : p;
            float coef = pos ? (1.f - pd[0]) : pd[0];
            acc0 += __logf(larg) * quad * quad * coef;
            succ_i += __popcll(__ballot((x0 > 0.f) == pos));
        }
        {
            float p = __builtin_amdgcn_rcpf(1.f + __expf(-x3));
            p = fminf(fmaxf(p, FEPS), 1.f - FEPS);
            float om = 1.f - p;
            bool pos = t[13] != 0;
            float larg = pos ? p : om;
            float quad = pos ? om : p;
            float coef = pos ? (1.f - pd[13]) : pd[13];
            acc3 += __logf(larg) * quad * quad * coef;
            succ_i += __popcll(__ballot((x3 > 0.f) == pos));
        }
        {
            float p = __builtin_amdgcn_rcpf(1.f + __expf(-x4));
            p = fminf(fmaxf(p, FEPS), 1.f - FEPS);
            float om = 1.f - p;
            bool pos = t[14] != 0;
            float larg = pos ? p : om;
            float quad = pos ? om : p;
            float coef = pos ? (1.f - pd[14]) : pd[14];
            acc4 += __logf(larg) * quad * quad * coef;
            succ_i += __popcll(__ballot((x4 > 0.f) == pos));
        }

        // ---- head 1: softmax probabilities (8) ----
        {
            const float o[8] = {pa.x, pa.y, pa.z, pa.w, pb.x, pb.y, pb.z, pb.w};
            int am_gt = 0;
#pragma unroll
            for (int j = 7; j >= 0; --j)
                if (t[1 + j] != 0) am_gt = j;               // first 1 (or 0 if none)
            float best = o[0];
            int am_o = 0;
#pragma unroll
            for (int j = 1; j < 8; ++j)
                if (o[j] > best) { best = o[j]; am_o = j; } // first max
#pragma unroll
            for (int j = 0; j < 8; ++j) {
                bool m = t[1 + j] != 0;
                float wsel = m ? (1.f - pd[1 + j]) : 0.f;   // weight-select, no mask mul
                float om = 1.f - o[j];
                acc1 += wsel * (__logf(o[j]) * om * om);
                cnt5_i += __popcll(__ballot(m));
            }
            succ_i += __popcll(__ballot(am_gt == am_o));
        }

        // ---- head 2: weighted BCE on logits (4) ----
        {
            const float o2v[4] = {q2.x, q2.y, q2.z, q2.w};
#pragma unroll
            for (int j = 0; j < 4; ++j) {
                float o = o2v[j];
                bool g = t[9 + j] != 0;
                float w = pd[9 + j];
                float weight = g ? (1.f - w) : w;
                float bce = fmaxf(o, 0.f) - (g ? o : 0.f)
                          + __logf(1.f + __expf(-fabsf(o)));
                acc2 += weight * bce;
                succ_i += __popcll(__ballot((o > 0.5f) == g));
            }
        }
    }

    // ---- block reduction: 5 float slots via shuffle; succ/cnt5 are wave-uniform ----
    {
        float accv[5] = {acc0, acc1, acc2, acc3, acc4};
#pragma unroll
        for (int k = 0; k < 5; ++k) {
            float v = wave_reduce_f(accv[k]);
            if (lane == 0) sred[wave][k] = v;
        }
    }
    __shared__ float scnt[4][2];
    if (lane == 0) {
        scnt[wave][0] = (float)cnt5_i;
        scnt[wave][1] = (float)succ_i;
    }
    __syncthreads();
    if (tid == 0) {
#pragma unroll
        for (int k = 0; k < 5; ++k) {
            float s = sred[0][k] + sred[1][k] + sred[2][k] + sred[3][k];
            partials[(long)blockIdx.x * 8 + k] = s;
        }
        partials[(long)blockIdx.x * 8 + 5] =
            scnt[0][0] + scnt[1][0] + scnt[2][0] + scnt[3][0];
        partials[(long)blockIdx.x * 8 + 6] =
            scnt[0][1] + scnt[1][1] + scnt[2][1] + scnt[3][1];
    }
}

__global__ __launch_bounds__(FINAL_NTH) void loss_final(
    const float* __restrict__ partials, int nblocks, float* __restrict__ out)
{
    double acc[7] = {0, 0, 0, 0, 0, 0, 0};
    for (int b = threadIdx.x; b < nblocks; b += FINAL_NTH) {
        const float4* pp = (const float4*)(partials + (long)b * 8);
        float4 a = pp[0], bb = pp[1];
        acc[0] += a.x; acc[1] += a.y; acc[2] += a.z; acc[3] += a.w;
        acc[4] += bb.x; acc[5] += bb.y; acc[6] += bb.z;
    }

    __shared__ double sd[4][7];
    const int lane = threadIdx.x & 63;
    const int wave = threadIdx.x >> 6;
#pragma unroll
    for (int k = 0; k < 7; ++k) {
        double v = wave_reduce_d(acc[k]);
        if (lane == 0) sd[wave][k] = v;
    }
    __syncthreads();
    if (threadIdx.x == 0) {
        double s[7];
#pragma unroll
        for (int k = 0; k < 7; ++k) s[k] = sd[0][k] + sd[1][k] + sd[2][k] + sd[3][k];

        const double Bd = (double)BROWS;
        double l0 = -(s[0] / Bd);
        double num = s[5];
        double l1 = (num > 0.0) ? -(s[1] / fmax(num, 1.0)) : 0.0;
        double l2 = s[2] / (Bd * 4.0);
        double l3 = -(s[3] / Bd);
        double l4 = -(s[4] / Bd);
        out[0] = (float)(l0 + l1 + l2 + l3 + l4);
        out[1] = (float)(s[6] / 8.0);
    }
}

extern "C" void kernel_launch(void* const* d_in, const int* in_sizes, int n_in,
                              void* d_out, int out_size, void* d_ws, size_t ws_size,
                              hipStream_t stream) {
    const float* out0 = (const float*)d_in[0];
    const float* out1 = (const float*)d_in[1];
    const float* out2 = (const float*)d_in[2];
    const float* out3 = (const float*)d_in[3];
    const float* out4 = (const float*)d_in[4];
    const float* pos_dist = (const float*)d_in[5];
    const int* targets = (const int*)d_in[6];
    float* out = (float*)d_out;
    float* partials = (float*)d_ws;

    loss_main<<<NBLOCKS, NTH, 0, stream>>>(
        out0, out1, out2, out3, out4, pos_dist, targets, partials);
    loss_final<<<1, FINAL_NTH, 0, stream>>>(partials, NBLOCKS, out);
}